// Round 5
// baseline (1904.058 us; speedup 1.0000x reference)
//
#include <hip/hip_runtime.h>
#include <math.h>
#include <float.h>

#define BN_EPS 1e-5f

// Exact (non-contracted) squared distance, matching numpy's mul-then-add
// left-to-right association. Critical: FPS/KNN *selections* must match ref.
__device__ __forceinline__ float sqdist_exact(float dx, float dy, float dz) {
  return __fadd_rn(__fadd_rn(__fmul_rn(dx, dx), __fmul_rn(dy, dy)), __fmul_rn(dz, dz));
}

// ---------------- MLP1: h1 = x @ W1  (3 -> 32) ----------------
__global__ void __launch_bounds__(256) mlp1_kernel(const float* __restrict__ x,
                                                   const float* __restrict__ W1,
                                                   float* __restrict__ h1, int rows) {
  int tid = blockIdx.x * 256 + threadIdx.x;
  int row = tid >> 5;
  int d = tid & 31;
  if (row >= rows) return;
  float x0 = x[row * 3 + 0], x1 = x[row * 3 + 1], x2 = x[row * 3 + 2];
  float acc = x0 * W1[d] + x1 * W1[32 + d] + x2 * W1[64 + d];
  h1[row * 32 + d] = acc;
}

// ---------------- per-channel sum/sumsq over flat (n, D) ----------------
__global__ void stats_kernel(const float* __restrict__ v, int n, int D,
                             float* __restrict__ partial) {
  int tid = blockIdx.x * blockDim.x + threadIdx.x;
  int stride = blockDim.x * gridDim.x;
  float s = 0.f, q = 0.f;
  for (int i = tid; i < n; i += stride) { float a = v[i]; s += a; q += a * a; }
  int c = tid % D;
  extern __shared__ float sm[];  // 2*D
  for (int i = threadIdx.x; i < 2 * D; i += blockDim.x) sm[i] = 0.f;
  __syncthreads();
  atomicAdd(&sm[c], s);
  atomicAdd(&sm[D + c], q);
  __syncthreads();
  for (int i = threadIdx.x; i < 2 * D; i += blockDim.x)
    atomicAdd(&partial[(blockIdx.x & 63) * 2 * D + i], sm[i]);
}

// ---------------- finalize: partial sums -> scale/shift ----------------
__global__ void finalize_kernel(const float* __restrict__ partial,
                                const float* __restrict__ g, const float* __restrict__ b,
                                float cnt, int D, float* __restrict__ ss) {
  int d = threadIdx.x;
  if (d >= D) return;
  float s = 0.f, q = 0.f;
  for (int j = 0; j < 64; j++) { s += partial[j * 2 * D + d]; q += partial[j * 2 * D + D + d]; }
  float mean = s / cnt;
  float var = q / cnt - mean * mean;
  var = fmaxf(var, 0.f);
  float sc = g[d] * rsqrtf(var + BN_EPS);
  ss[d] = sc;
  ss[D + d] = b[d] - mean * sc;
}

// ---------------- apply BN+ReLU to pooled max/min (in-place on vmax) ----------------
__global__ void bn_apply_kernel(float* __restrict__ vmax, const float* __restrict__ vmin,
                                const float* __restrict__ ss, int D, int n) {
  int tid = blockIdx.x * blockDim.x + threadIdx.x;
  int stride = blockDim.x * gridDim.x;
  for (int i = tid; i < n; i += stride) {
    int d = i % D;
    float sc = ss[d], sh = ss[D + d];
    float v = (sc >= 0.f) ? vmax[i] : vmin[i];
    vmax[i] = fmaxf(v * sc + sh, 0.f);
  }
}

// ---------------- FPS v5: coords travel with candidates ----------------
// Key = (float_bits(dist) << 32) | ~index  (dist>=0 => IEEE order == uint
// order; max key == max dist, first-index tie-break == jnp.argmax).
// The serial scan carries (bv,bi,bx,by,bz); after the 6-step DPP wave
// reduce the owner lane has the winner coords in registers. NW>1: owner
// writes (key,x,y,z) to its wave slot; one barrier; each lane reads slot
// (lane&(NW-1)) and a 2-step quad_perm DPP merge hands every lane the
// block winner key+coords. No dependent second LDS read, no spts staging.
#define DPP_STEP(CTRL)                                                                   \
  {                                                                                      \
    unsigned int nhi = (unsigned int)__builtin_amdgcn_update_dpp((int)khi, (int)khi,     \
                                                                 CTRL, 0xf, 0xf, false); \
    unsigned int nlo = (unsigned int)__builtin_amdgcn_update_dpp((int)klo, (int)klo,     \
                                                                 CTRL, 0xf, 0xf, false); \
    unsigned long long nk = (((unsigned long long)nhi) << 32) | nlo;                     \
    if (nk > wk) { wk = nk; khi = nhi; klo = nlo; }                                      \
  }

#define QP_MERGE(CTRL)                                                                    \
  {                                                                                       \
    unsigned int nhi = (unsigned int)__builtin_amdgcn_update_dpp((int)mhi, (int)mhi,      \
                                                                 CTRL, 0xf, 0xf, false);  \
    unsigned int nlo = (unsigned int)__builtin_amdgcn_update_dpp((int)mlo, (int)mlo,      \
                                                                 CTRL, 0xf, 0xf, false);  \
    int nxi = __builtin_amdgcn_update_dpp(__float_as_int(mx), __float_as_int(mx),         \
                                          CTRL, 0xf, 0xf, false);                         \
    int nyi = __builtin_amdgcn_update_dpp(__float_as_int(my2), __float_as_int(my2),       \
                                          CTRL, 0xf, 0xf, false);                         \
    int nzi = __builtin_amdgcn_update_dpp(__float_as_int(mz), __float_as_int(mz),         \
                                          CTRL, 0xf, 0xf, false);                         \
    unsigned long long ck = (((unsigned long long)mhi) << 32) | mlo;                      \
    unsigned long long nk = (((unsigned long long)nhi) << 32) | nlo;                      \
    if (nk > ck) {                                                                        \
      mhi = nhi; mlo = nlo;                                                               \
      mx = __int_as_float(nxi); my2 = __int_as_float(nyi); mz = __int_as_float(nzi);      \
    }                                                                                     \
  }

template <int P, int NW>
__global__ void __launch_bounds__(NW * 64) fps5_kernel(const float* __restrict__ p,
                                                       float* __restrict__ newp) {
  constexpr int BS = NW * 64;
  constexpr int N = P * BS;
  constexpr int M = N / 4;
  __shared__ __align__(32) float slots[NW > 1 ? 2 * NW * 8 : 8];
  __shared__ float snew[NW > 1 ? M * 3 : 3];
  const int b = blockIdx.x;
  const int t = threadIdx.x;
  const int wv = t >> 6;
  const int lane = t & 63;
  const float* pb = p + (size_t)b * N * 3;
  float px[P], py[P], pz[P], md[P];
#pragma unroll
  for (int j = 0; j < P; j++) {
    int i = j * BS + t;
    px[j] = pb[3 * i]; py[j] = pb[3 * i + 1]; pz[j] = pb[3 * i + 2];
    md[j] = INFINITY;
  }
  float lx = pb[0], ly = pb[1], lz = pb[2];
  if (t == 0) {
    if constexpr (NW > 1) {
      snew[0] = lx; snew[1] = ly; snew[2] = lz;
    } else {
      newp[(size_t)b * M * 3 + 0] = lx;
      newp[(size_t)b * M * 3 + 1] = ly;
      newp[(size_t)b * M * 3 + 2] = lz;
    }
  }

  for (int r = 1; r < M; r++) {
    // serial scan carrying (bv, bi, bx, by, bz)
    float bv, bx, by, bz; int bi;
    {
      float d0 = sqdist_exact(px[0] - lx, py[0] - ly, pz[0] - lz);
      float m0 = fminf(md[0], d0);
      md[0] = m0;
      bv = m0; bi = t; bx = px[0]; by = py[0]; bz = pz[0];
    }
#pragma unroll
    for (int j = 1; j < P; j++) {
      float d = sqdist_exact(px[j] - lx, py[j] - ly, pz[j] - lz);
      float m = fminf(md[j], d);
      md[j] = m;
      if (m > bv) {  // strict >: first-index ties within lane
        bv = m; bi = j * BS + t; bx = px[j]; by = py[j]; bz = pz[j];
      }
    }
    unsigned int khi = __float_as_uint(bv);
    unsigned int klo = ~(unsigned int)bi;
    const unsigned int myhi = khi, mylo = klo;
    unsigned long long wk = (((unsigned long long)khi) << 32) | klo;
    DPP_STEP(0x111);  // row_shr:1
    DPP_STEP(0x112);  // row_shr:2
    DPP_STEP(0x114);  // row_shr:4
    DPP_STEP(0x118);  // row_shr:8
    DPP_STEP(0x142);  // row_bcast:15
    DPP_STEP(0x143);  // row_bcast:31
    // lane 63 holds the wave max; broadcast key to all lanes (SALU)
    unsigned int whi = (unsigned int)__builtin_amdgcn_readlane((int)(wk >> 32), 63);
    unsigned int wlo = (unsigned int)__builtin_amdgcn_readlane((int)wk, 63);

    if constexpr (NW == 1) {
      int owner = (int)((~wlo) & 63u);
      lx = __int_as_float(__builtin_amdgcn_readlane(__float_as_int(bx), owner));
      ly = __int_as_float(__builtin_amdgcn_readlane(__float_as_int(by), owner));
      lz = __int_as_float(__builtin_amdgcn_readlane(__float_as_int(bz), owner));
      if (t == 0) {
        size_t o = ((size_t)b * M + r) * 3;
        newp[o] = lx; newp[o + 1] = ly; newp[o + 2] = lz;
      }
    } else {
      float* base = slots + (r & 1) * NW * 8;
      if (myhi == whi && mylo == wlo) {  // unique owner lane of this wave
        float4 v = make_float4(__uint_as_float(whi), __uint_as_float(wlo), bx, by);
        *reinterpret_cast<float4*>(base + wv * 8) = v;
        base[wv * 8 + 4] = bz;
      }
      __syncthreads();
      const float* sl = base + (lane & (NW - 1)) * 8;
      const float4 s4 = *reinterpret_cast<const float4*>(sl);
      float mz = sl[4];
      unsigned int mhi = __float_as_uint(s4.x), mlo = __float_as_uint(s4.y);
      float mx = s4.z, my2 = s4.w;
      if constexpr (NW >= 2) QP_MERGE(0xB1);  // quad_perm (1,0,3,2)
      if constexpr (NW >= 4) QP_MERGE(0x4E);  // quad_perm (2,3,0,1)
      lx = mx; ly = my2; lz = mz;
      if (t == 0) {
        snew[3 * r] = lx; snew[3 * r + 1] = ly; snew[3 * r + 2] = lz;
      }
    }
  }
  if constexpr (NW > 1) {
    __syncthreads();
    for (int i = t; i < M * 3; i += BS) newp[(size_t)b * M * 3 + i] = snew[i];
  }
}

// ---------------- KNN: one wave per query, top-16 smallest distances ----------------
__global__ void __launch_bounds__(256) knn_kernel(const float* __restrict__ p,
                                                  const float* __restrict__ newp,
                                                  int N, int M, int BM,
                                                  int* __restrict__ nidx) {
  int gwid = (blockIdx.x * 256 + threadIdx.x) >> 6;
  int lane = threadIdx.x & 63;
  if (gwid >= BM) return;
  int b = gwid / M;
  const float* pb = p + (size_t)b * N * 3;
  float qx = newp[(size_t)gwid * 3], qy = newp[(size_t)gwid * 3 + 1], qz = newp[(size_t)gwid * 3 + 2];
  float bd[16];
  int bi[16];
#pragma unroll
  for (int s = 0; s < 16; s++) { bd[s] = INFINITY; bi[s] = 0x7FFFFFFF; }
  for (int c = lane; c < N; c += 64) {
    float d = sqdist_exact(pb[3 * c] - qx, pb[3 * c + 1] - qy, pb[3 * c + 2] - qz);
    if (d < bd[15]) {
      bd[15] = d; bi[15] = c;
#pragma unroll
      for (int s = 15; s >= 1; --s) {
        bool sw = bd[s] < bd[s - 1];
        if (sw) {
          float tf = bd[s]; bd[s] = bd[s - 1]; bd[s - 1] = tf;
          int ti = bi[s]; bi[s] = bi[s - 1]; bi[s - 1] = ti;
        }
      }
    }
  }
  int out = 0;
  for (int r = 0; r < 16; r++) {
    float v = bd[0]; int ii = bi[0];
    float mv = v; int mi = ii;
#pragma unroll
    for (int m = 1; m < 64; m <<= 1) {
      float v2 = __shfl_xor(mv, m);
      int i2 = __shfl_xor(mi, m);
      if (v2 < mv || (v2 == mv && i2 < mi)) { mv = v2; mi = i2; }
    }
    if (mi == ii) {
#pragma unroll
      for (int s = 0; s < 15; s++) { bd[s] = bd[s + 1]; bi[s] = bi[s + 1]; }
      bd[15] = INFINITY; bi[15] = 0x7FFFFFFF;
    }
    if (lane == r) out = mi;
  }
  if (lane < 16) nidx[(size_t)gwid * 16 + lane] = out;
}

// ---------------- gather + GEMM + stats + max/min pool over k=16 ----------------
__global__ void __launch_bounds__(256) gemm_kernel(
    const float* __restrict__ p, const float* __restrict__ h, const float* __restrict__ newp,
    const int* __restrict__ nidx, const float* __restrict__ W,
    float* __restrict__ ymax, float* __restrict__ ymin, float* __restrict__ partial,
    int N, int M, int BM, int Ch, int Cpad, int D, int Gseq) {
  extern __shared__ float sm[];
  int Ctot = Ch + 3;
  int TD = D < 256 ? D : 256;
  int Gpar = 256 / TD;
  float* sfeat = sm;                      // Gpar*16*Cpad
  float* sstat = sm + Gpar * 16 * Cpad;   // 2*D
  int t = threadIdx.x;
  for (int i = t; i < 2 * D; i += 256) sstat[i] = 0.f;
  int mloc = t / TD;
  int dbase = t % TD;
  int DV = D / TD;  // 1 or 2
  __syncthreads();
  for (int s = 0; s < Gseq; s++) {
    int grp0 = (blockIdx.x * Gseq + s) * Gpar;
    if (grp0 >= BM) break;
    int nf = Gpar * 16 * Cpad;
    for (int i = t; i < nf; i += 256) {
      int c = i % Cpad;
      int rk = i / Cpad;
      int k = rk & 15;
      int g = rk >> 4;
      int grp = grp0 + g;
      float val = 0.f;
      if (grp < BM && c < Ctot) {
        int b = grp / M;
        int nb = nidx[(size_t)grp * 16 + k];
        if (c < 3)
          val = p[((size_t)b * N + nb) * 3 + c] - newp[(size_t)grp * 3 + c];
        else
          val = h[((size_t)b * N + nb) * Ch + (c - 3)];
      }
      sfeat[i] = val;
    }
    __syncthreads();
    int grp = grp0 + mloc;
    bool act = grp < BM;
    const float* fr = sfeat + mloc * 16 * Cpad;
    for (int dv = 0; dv < DV; ++dv) {
      int d = dbase + (dv << 8);
      float acc[16];
#pragma unroll
      for (int k = 0; k < 16; k++) acc[k] = 0.f;
      for (int c = 0; c < Cpad; c += 4) {
        float w0 = (c < Ctot) ? W[(size_t)c * D + d] : 0.f;
        float w1 = (c + 1 < Ctot) ? W[(size_t)(c + 1) * D + d] : 0.f;
        float w2 = (c + 2 < Ctot) ? W[(size_t)(c + 2) * D + d] : 0.f;
        float w3 = (c + 3 < Ctot) ? W[(size_t)(c + 3) * D + d] : 0.f;
#pragma unroll
        for (int k = 0; k < 16; k++) {
          const float4 f = *reinterpret_cast<const float4*>(fr + k * Cpad + c);
          acc[k] += f.x * w0 + f.y * w1 + f.z * w2 + f.w * w3;
        }
      }
      if (act) {
        float ssum = 0.f, ssq = 0.f, amax = -INFINITY, amin = INFINITY;
#pragma unroll
        for (int k = 0; k < 16; k++) {
          float a = acc[k];
          ssum += a; ssq += a * a;
          amax = fmaxf(amax, a); amin = fminf(amin, a);
        }
        ymax[(size_t)grp * D + d] = amax;
        ymin[(size_t)grp * D + d] = amin;
        atomicAdd(&sstat[d], ssum);
        atomicAdd(&sstat[D + d], ssq);
      }
    }
    __syncthreads();
  }
  for (int i = t; i < 2 * D; i += 256)
    atomicAdd(&partial[(blockIdx.x & 63) * 2 * D + i], sstat[i]);
}

// ---------------- classifier head: mean-pool + 3 layers, single block ----------------
__global__ void __launch_bounds__(512) classifier_kernel(
    const float* __restrict__ h4,
    const float* __restrict__ Wc1, const float* __restrict__ bc1,
    const float* __restrict__ gc1, const float* __restrict__ hc1,
    const float* __restrict__ Wc2, const float* __restrict__ bc2,
    const float* __restrict__ gc2, const float* __restrict__ hc2,
    const float* __restrict__ Wc3, const float* __restrict__ bc3,
    float* __restrict__ out) {
  __shared__ float z[16 * 512];
  __shared__ float z1[16 * 256];
  __shared__ float z2[16 * 128];
  __shared__ float sc[256], sh[256];
  int t = threadIdx.x;
  for (int i = t; i < 16 * 512; i += 512) {
    int b = i >> 9, c = i & 511;
    float s = 0.f;
    for (int k = 0; k < 16; k++) s += h4[((size_t)b * 16 + k) * 512 + c];
    z[i] = s * (1.f / 16.f);
  }
  __syncthreads();
  for (int i = t; i < 16 * 256; i += 512) {
    int b = i >> 8, d = i & 255;
    float a = bc1[d];
    for (int c = 0; c < 512; c++) a += z[(b << 9) + c] * Wc1[c * 256 + d];
    z1[i] = a;
  }
  __syncthreads();
  if (t < 256) {
    float s = 0.f, q = 0.f;
    for (int b = 0; b < 16; b++) { float a = z1[(b << 8) + t]; s += a; q += a * a; }
    float mean = s * (1.f / 16.f);
    float var = fmaxf(q * (1.f / 16.f) - mean * mean, 0.f);
    float scl = gc1[t] * rsqrtf(var + BN_EPS);
    sc[t] = scl; sh[t] = hc1[t] - mean * scl;
  }
  __syncthreads();
  for (int i = t; i < 16 * 256; i += 512) {
    int d = i & 255;
    z1[i] = fmaxf(z1[i] * sc[d] + sh[d], 0.f);
  }
  __syncthreads();
  for (int i = t; i < 16 * 128; i += 512) {
    int b = i >> 7, d = i & 127;
    float a = bc2[d];
    for (int c = 0; c < 256; c++) a += z1[(b << 8) + c] * Wc2[c * 128 + d];
    z2[i] = a;
  }
  __syncthreads();
  if (t < 128) {
    float s = 0.f, q = 0.f;
    for (int b = 0; b < 16; b++) { float a = z2[(b << 7) + t]; s += a; q += a * a; }
    float mean = s * (1.f / 16.f);
    float var = fmaxf(q * (1.f / 16.f) - mean * mean, 0.f);
    float scl = gc2[t] * rsqrtf(var + BN_EPS);
    sc[t] = scl; sh[t] = hc2[t] - mean * scl;
  }
  __syncthreads();
  for (int i = t; i < 16 * 128; i += 512) {
    int d = i & 127;
    z2[i] = fmaxf(z2[i] * sc[d] + sh[d], 0.f);
  }
  __syncthreads();
  for (int i = t; i < 640; i += 512) {
    int b = i / 40, d = i % 40;
    float a = bc3[d];
    for (int c = 0; c < 128; c++) a += z2[(b << 7) + c] * Wc3[c * 40 + d];
    out[i] = a;
  }
}

extern "C" void kernel_launch(void* const* d_in, const int* in_sizes, int n_in,
                              void* d_out, int out_size, void* d_ws, size_t ws_size,
                              hipStream_t stream) {
  (void)in_sizes; (void)n_in; (void)out_size; (void)ws_size;
  const float* x   = (const float*)d_in[0];
  const float* W1  = (const float*)d_in[1];
  const float* g1  = (const float*)d_in[2];
  const float* b1  = (const float*)d_in[3];
  const float* W2  = (const float*)d_in[4];
  const float* g2  = (const float*)d_in[5];
  const float* b2  = (const float*)d_in[6];
  const float* W3  = (const float*)d_in[7];
  const float* g3  = (const float*)d_in[8];
  const float* b3  = (const float*)d_in[9];
  const float* W4  = (const float*)d_in[10];
  const float* g4  = (const float*)d_in[11];
  const float* b4  = (const float*)d_in[12];
  const float* W5  = (const float*)d_in[13];
  const float* g5  = (const float*)d_in[14];
  const float* b5  = (const float*)d_in[15];
  const float* Wc1 = (const float*)d_in[16];
  const float* bc1 = (const float*)d_in[17];
  const float* gc1 = (const float*)d_in[18];
  const float* hc1 = (const float*)d_in[19];
  const float* Wc2 = (const float*)d_in[20];
  const float* bc2 = (const float*)d_in[21];
  const float* gc2 = (const float*)d_in[22];
  const float* hc2 = (const float*)d_in[23];
  const float* Wc3 = (const float*)d_in[24];
  const float* bc3 = (const float*)d_in[25];
  float* out = (float*)d_out;

  float* ws = (float*)d_ws;
  float* HA   = ws;                  // 2,097,152 (h1; stage2 out; stage4 out)
  float* HB   = HA + 2097152;        // 1,048,576 (stage1 out; stage3 out)
  float* YMIN = HB + 1048576;        // 1,048,576
  float* NP1  = YMIN + 1048576;      // 49,152
  float* NP2  = NP1 + 49152;         // 12,288
  float* NP3  = NP2 + 12288;         // 3,072
  float* NP4  = NP3 + 3072;          // 768
  int*   NIDX = (int*)(NP4 + 768);   // 262,144 ints
  float* PART = (float*)(NIDX + 262144);  // 5 * 65,536
  float* SS   = PART + 5 * 65536;         // 5 * 1,024

  hipMemsetAsync(PART, 0, 5 * 65536 * sizeof(float), stream);

  // --- MLP1 + BN(axes 0,1) + ReLU ---
  mlp1_kernel<<<(65536 * 32) / 256, 256, 0, stream>>>(x, W1, HA, 65536);
  stats_kernel<<<256, 256, 2 * 32 * sizeof(float), stream>>>(HA, 65536 * 32, 32, PART);
  finalize_kernel<<<1, 32, 0, stream>>>(PART, g1, b1, 65536.f, 32, SS);
  bn_apply_kernel<<<512, 256, 0, stream>>>(HA, HA, SS, 32, 65536 * 32);

  // --- stage 1: N=4096 -> M=1024, Ch=32 -> D=64 ---
  fps5_kernel<16, 4><<<16, 256, 0, stream>>>(x, NP1);
  knn_kernel<<<(16384 + 3) / 4, 256, 0, stream>>>(x, NP1, 4096, 1024, 16384, NIDX);
  gemm_kernel<<<512, 256, (4 * 16 * 36 + 2 * 64) * sizeof(float), stream>>>(
      x, HA, NP1, NIDX, W2, HB, YMIN, PART + 65536, 4096, 1024, 16384, 32, 36, 64, 8);
  finalize_kernel<<<1, 64, 0, stream>>>(PART + 65536, g2, b2, (float)(16384 * 16), 64, SS + 1024);
  bn_apply_kernel<<<512, 256, 0, stream>>>(HB, YMIN, SS + 1024, 64, 16384 * 64);

  // --- stage 2: N=1024 -> M=256, Ch=64 -> D=128 ---
  fps5_kernel<16, 1><<<16, 64, 0, stream>>>(NP1, NP2);
  knn_kernel<<<(4096 + 3) / 4, 256, 0, stream>>>(NP1, NP2, 1024, 256, 4096, NIDX);
  gemm_kernel<<<512, 256, (2 * 16 * 68 + 2 * 128) * sizeof(float), stream>>>(
      NP1, HB, NP2, NIDX, W3, HA, YMIN, PART + 2 * 65536, 1024, 256, 4096, 64, 68, 128, 4);
  finalize_kernel<<<1, 128, 0, stream>>>(PART + 2 * 65536, g3, b3, (float)(4096 * 16), 128, SS + 2048);
  bn_apply_kernel<<<512, 256, 0, stream>>>(HA, YMIN, SS + 2048, 128, 4096 * 128);

  // --- stage 3: N=256 -> M=64, Ch=128 -> D=256 ---
  fps5_kernel<4, 1><<<16, 64, 0, stream>>>(NP2, NP3);
  knn_kernel<<<(1024 + 3) / 4, 256, 0, stream>>>(NP2, NP3, 256, 64, 1024, NIDX);
  gemm_kernel<<<512, 256, (16 * 132 + 2 * 256) * sizeof(float), stream>>>(
      NP2, HA, NP3, NIDX, W4, HB, YMIN, PART + 3 * 65536, 256, 64, 1024, 128, 132, 256, 2);
  finalize_kernel<<<1, 256, 0, stream>>>(PART + 3 * 65536, g4, b4, (float)(1024 * 16), 256, SS + 3072);
  bn_apply_kernel<<<512, 256, 0, stream>>>(HB, YMIN, SS + 3072, 256, 1024 * 256);

  // --- stage 4: N=64 -> M=16, Ch=256 -> D=512 ---
  fps5_kernel<1, 1><<<16, 64, 0, stream>>>(NP3, NP4);
  knn_kernel<<<(256 + 3) / 4, 256, 0, stream>>>(NP3, NP4, 64, 16, 256, NIDX);
  gemm_kernel<<<256, 256, (16 * 260 + 2 * 512) * sizeof(float), stream>>>(
      NP3, HB, NP4, NIDX, W5, HA, YMIN, PART + 4 * 65536, 64, 16, 256, 256, 260, 512, 1);
  finalize_kernel<<<1, 512, 0, stream>>>(PART + 4 * 65536, g5, b5, (float)(256 * 16), 512, SS + 4096);
  bn_apply_kernel<<<512, 256, 0, stream>>>(HA, YMIN, SS + 4096, 512, 256 * 512);

  // --- classifier head ---
  classifier_kernel<<<1, 512, 0, stream>>>(HA, Wc1, bc1, gc1, hc1, Wc2, bc2, gc2, hc2, Wc3, bc3, out);
}

// Round 6
// 1854.226 us; speedup vs baseline: 1.0269x; 1.0269x over previous
//
#include <hip/hip_runtime.h>
#include <math.h>
#include <float.h>

#define BN_EPS 1e-5f

// Exact (non-contracted) squared distance, matching numpy's mul-then-add
// left-to-right association. Critical: FPS/KNN *selections* must match ref.
__device__ __forceinline__ float sqdist_exact(float dx, float dy, float dz) {
  return __fadd_rn(__fadd_rn(__fmul_rn(dx, dx), __fmul_rn(dy, dy)), __fmul_rn(dz, dz));
}

// ---------------- MLP1: h1 = x @ W1  (3 -> 32) ----------------
__global__ void __launch_bounds__(256) mlp1_kernel(const float* __restrict__ x,
                                                   const float* __restrict__ W1,
                                                   float* __restrict__ h1, int rows) {
  int tid = blockIdx.x * 256 + threadIdx.x;
  int row = tid >> 5;
  int d = tid & 31;
  if (row >= rows) return;
  float x0 = x[row * 3 + 0], x1 = x[row * 3 + 1], x2 = x[row * 3 + 2];
  float acc = x0 * W1[d] + x1 * W1[32 + d] + x2 * W1[64 + d];
  h1[row * 32 + d] = acc;
}

// ---------------- per-channel sum/sumsq over flat (n, D) ----------------
__global__ void stats_kernel(const float* __restrict__ v, int n, int D,
                             float* __restrict__ partial) {
  int tid = blockIdx.x * blockDim.x + threadIdx.x;
  int stride = blockDim.x * gridDim.x;
  float s = 0.f, q = 0.f;
  for (int i = tid; i < n; i += stride) { float a = v[i]; s += a; q += a * a; }
  int c = tid % D;
  extern __shared__ float sm[];  // 2*D
  for (int i = threadIdx.x; i < 2 * D; i += blockDim.x) sm[i] = 0.f;
  __syncthreads();
  atomicAdd(&sm[c], s);
  atomicAdd(&sm[D + c], q);
  __syncthreads();
  for (int i = threadIdx.x; i < 2 * D; i += blockDim.x)
    atomicAdd(&partial[(blockIdx.x & 63) * 2 * D + i], sm[i]);
}

// ---------------- finalize: partial sums -> scale/shift ----------------
__global__ void finalize_kernel(const float* __restrict__ partial,
                                const float* __restrict__ g, const float* __restrict__ b,
                                float cnt, int D, float* __restrict__ ss) {
  int d = threadIdx.x;
  if (d >= D) return;
  float s = 0.f, q = 0.f;
  for (int j = 0; j < 64; j++) { s += partial[j * 2 * D + d]; q += partial[j * 2 * D + D + d]; }
  float mean = s / cnt;
  float var = q / cnt - mean * mean;
  var = fmaxf(var, 0.f);
  float sc = g[d] * rsqrtf(var + BN_EPS);
  ss[d] = sc;
  ss[D + d] = b[d] - mean * sc;
}

// ---------------- apply BN+ReLU to pooled max/min (in-place on vmax) ----------------
__global__ void bn_apply_kernel(float* __restrict__ vmax, const float* __restrict__ vmin,
                                const float* __restrict__ ss, int D, int n) {
  int tid = blockIdx.x * blockDim.x + threadIdx.x;
  int stride = blockDim.x * gridDim.x;
  for (int i = tid; i < n; i += stride) {
    int d = i % D;
    float sc = ss[d], sh = ss[D + d];
    float v = (sc >= 0.f) ? vmax[i] : vmin[i];
    vmax[i] = fmaxf(v * sc + sh, 0.f);
  }
}

// Key = (float_bits(dist) << 32) | ~index  (dist>=0 => IEEE order == uint
// order; max key == max dist, first-index tie-break == jnp.argmax).
#define DPP_STEP(CTRL)                                                                   \
  {                                                                                      \
    unsigned int nhi = (unsigned int)__builtin_amdgcn_update_dpp((int)khi, (int)khi,     \
                                                                 CTRL, 0xf, 0xf, false); \
    unsigned int nlo = (unsigned int)__builtin_amdgcn_update_dpp((int)klo, (int)klo,     \
                                                                 CTRL, 0xf, 0xf, false); \
    unsigned long long nk = (((unsigned long long)nhi) << 32) | nlo;                     \
    if (nk > wk) { wk = nk; khi = nhi; klo = nlo; }                                      \
  }

#define QP_MERGE(CTRL)                                                                    \
  {                                                                                       \
    unsigned int nhi = (unsigned int)__builtin_amdgcn_update_dpp((int)mhi, (int)mhi,      \
                                                                 CTRL, 0xf, 0xf, false);  \
    unsigned int nlo = (unsigned int)__builtin_amdgcn_update_dpp((int)mlo, (int)mlo,      \
                                                                 CTRL, 0xf, 0xf, false);  \
    int nxi = __builtin_amdgcn_update_dpp(__float_as_int(mx), __float_as_int(mx),         \
                                          CTRL, 0xf, 0xf, false);                         \
    int nyi = __builtin_amdgcn_update_dpp(__float_as_int(my2), __float_as_int(my2),       \
                                          CTRL, 0xf, 0xf, false);                         \
    int nzi = __builtin_amdgcn_update_dpp(__float_as_int(mz), __float_as_int(mz),         \
                                          CTRL, 0xf, 0xf, false);                         \
    unsigned long long ck = (((unsigned long long)mhi) << 32) | mlo;                      \
    unsigned long long nk = (((unsigned long long)nhi) << 32) | nlo;                      \
    if (nk > ck) {                                                                        \
      mhi = nhi; mlo = nlo;                                                               \
      mx = __int_as_float(nxi); my2 = __int_as_float(nyi); mz = __int_as_float(nzi);      \
    }                                                                                     \
  }

// ---------------- FPS v6 (stage 1): NW=8/P=8, max-tree scan select,
// u64 DPP wave reduce, coords-in-slot block merge (single LDS round-trip).
__global__ void __launch_bounds__(512) fps6_kernel(const float* __restrict__ p,
                                                   float* __restrict__ newp) {
  constexpr int P = 8, NW = 8;
  constexpr int BS = NW * 64;   // 512
  constexpr int N = P * BS;     // 4096
  constexpr int M = N / 4;      // 1024
  __shared__ __align__(32) float slots[2 * NW * 8];
  __shared__ float snew[M * 3];
  const int b = blockIdx.x;
  const int t = threadIdx.x;
  const int wv = t >> 6;
  const int lane = t & 63;
  const float* pb = p + (size_t)b * N * 3;
  float px[P], py[P], pz[P], md[P];
#pragma unroll
  for (int j = 0; j < P; j++) {
    int i = j * BS + t;
    px[j] = pb[3 * i]; py[j] = pb[3 * i + 1]; pz[j] = pb[3 * i + 2];
    md[j] = INFINITY;
  }
  float lx = pb[0], ly = pb[1], lz = pb[2];
  if (t == 0) { snew[0] = lx; snew[1] = ly; snew[2] = lz; }

  for (int r = 1; r < M; r++) {
    // distance + min-dist update (independent per j)
#pragma unroll
    for (int j = 0; j < P; j++) {
      float d = sqdist_exact(px[j] - lx, py[j] - ly, pz[j] - lz);
      md[j] = fminf(md[j], d);
    }
    // shallow max tree (depth 3)
    float m01 = fmaxf(md[0], md[1]);
    float m23 = fmaxf(md[2], md[3]);
    float m45 = fmaxf(md[4], md[5]);
    float m67 = fmaxf(md[6], md[7]);
    float m03 = fmaxf(m01, m23);
    float m47 = fmaxf(m45, m67);
    float bv = fmaxf(m03, m47);
    // smallest local j achieving bv (backward equality scan)
    int bj = P - 1;
#pragma unroll
    for (int j = P - 2; j >= 0; --j) bj = (md[j] == bv) ? j : bj;

    unsigned int khi = __float_as_uint(bv);
    unsigned int klo = ~(unsigned int)(bj * BS + t);
    const unsigned int myhi = khi, mylo = klo;
    unsigned long long wk = (((unsigned long long)khi) << 32) | klo;
    DPP_STEP(0x111);  // row_shr:1
    DPP_STEP(0x112);  // row_shr:2
    DPP_STEP(0x114);  // row_shr:4
    DPP_STEP(0x118);  // row_shr:8
    DPP_STEP(0x142);  // row_bcast:15
    DPP_STEP(0x143);  // row_bcast:31
    unsigned int whi = (unsigned int)__builtin_amdgcn_readlane((int)(wk >> 32), 63);
    unsigned int wlo = (unsigned int)__builtin_amdgcn_readlane((int)wk, 63);

    // owner-coord select: depth-3 cndmask tree on bj (all lanes execute)
    bool s0 = (bj & 1) != 0, s1 = (bj & 2) != 0, s2 = (bj & 4) != 0;
    float x01 = s0 ? px[1] : px[0], x23 = s0 ? px[3] : px[2];
    float x45 = s0 ? px[5] : px[4], x67 = s0 ? px[7] : px[6];
    float y01 = s0 ? py[1] : py[0], y23 = s0 ? py[3] : py[2];
    float y45 = s0 ? py[5] : py[4], y67 = s0 ? py[7] : py[6];
    float z01 = s0 ? pz[1] : pz[0], z23 = s0 ? pz[3] : pz[2];
    float z45 = s0 ? pz[5] : pz[4], z67 = s0 ? pz[7] : pz[6];
    float x03 = s1 ? x23 : x01, x47 = s1 ? x67 : x45;
    float y03 = s1 ? y23 : y01, y47 = s1 ? y67 : y45;
    float z03 = s1 ? z23 : z01, z47 = s1 ? z67 : z45;
    float sx = s2 ? x47 : x03, sy = s2 ? y47 : y03, sz = s2 ? z47 : z03;

    float* base = slots + (r & 1) * NW * 8;
    if (myhi == whi && mylo == wlo) {  // unique owner lane of this wave
      float4 v = make_float4(__uint_as_float(whi), __uint_as_float(wlo), sx, sy);
      *reinterpret_cast<float4*>(base + wv * 8) = v;
      base[wv * 8 + 4] = sz;
    }
    __syncthreads();
    // each lane reads 2 of the 8 slots (conflict-free; broadcast across quads)
    const float* sa = base + (lane & 3) * 8;
    const float* sb = base + ((lane & 3) + 4) * 8;
    float4 a4 = *reinterpret_cast<const float4*>(sa);
    float az = sa[4];
    float4 b4 = *reinterpret_cast<const float4*>(sb);
    float bz2 = sb[4];
    unsigned long long ka = (((unsigned long long)__float_as_uint(a4.x)) << 32) |
                            __float_as_uint(a4.y);
    unsigned long long kb = (((unsigned long long)__float_as_uint(b4.x)) << 32) |
                            __float_as_uint(b4.y);
    if (kb > ka) { ka = kb; a4 = b4; az = bz2; }
    unsigned int mhi = (unsigned int)(ka >> 32), mlo = (unsigned int)ka;
    float mx = a4.z, my2 = a4.w, mz = az;
    QP_MERGE(0xB1);  // quad_perm (1,0,3,2)
    QP_MERGE(0x4E);  // quad_perm (2,3,0,1)
    lx = mx; ly = my2; lz = mz;
    if (t == 0) { snew[3 * r] = lx; snew[3 * r + 1] = ly; snew[3 * r + 2] = lz; }
  }
  __syncthreads();
  for (int i = t; i < M * 3; i += BS) newp[(size_t)b * M * 3 + i] = snew[i];
}

// ---------------- FPS v5 (NW=1 stages): coords travel with candidates ----------------
template <int P>
__global__ void __launch_bounds__(64) fps5_kernel(const float* __restrict__ p,
                                                  float* __restrict__ newp) {
  constexpr int BS = 64;
  constexpr int N = P * BS;
  constexpr int M = N / 4;
  const int b = blockIdx.x;
  const int t = threadIdx.x;
  const float* pb = p + (size_t)b * N * 3;
  float px[P], py[P], pz[P], md[P];
#pragma unroll
  for (int j = 0; j < P; j++) {
    int i = j * BS + t;
    px[j] = pb[3 * i]; py[j] = pb[3 * i + 1]; pz[j] = pb[3 * i + 2];
    md[j] = INFINITY;
  }
  float lx = pb[0], ly = pb[1], lz = pb[2];
  if (t == 0) {
    newp[(size_t)b * M * 3 + 0] = lx;
    newp[(size_t)b * M * 3 + 1] = ly;
    newp[(size_t)b * M * 3 + 2] = lz;
  }
  for (int r = 1; r < M; r++) {
    float bv, bx, by, bz; int bi;
    {
      float d0 = sqdist_exact(px[0] - lx, py[0] - ly, pz[0] - lz);
      float m0 = fminf(md[0], d0);
      md[0] = m0;
      bv = m0; bi = t; bx = px[0]; by = py[0]; bz = pz[0];
    }
#pragma unroll
    for (int j = 1; j < P; j++) {
      float d = sqdist_exact(px[j] - lx, py[j] - ly, pz[j] - lz);
      float m = fminf(md[j], d);
      md[j] = m;
      if (m > bv) { bv = m; bi = j * BS + t; bx = px[j]; by = py[j]; bz = pz[j]; }
    }
    unsigned int khi = __float_as_uint(bv);
    unsigned int klo = ~(unsigned int)bi;
    unsigned long long wk = (((unsigned long long)khi) << 32) | klo;
    DPP_STEP(0x111);
    DPP_STEP(0x112);
    DPP_STEP(0x114);
    DPP_STEP(0x118);
    DPP_STEP(0x142);
    DPP_STEP(0x143);
    unsigned int wlo = (unsigned int)__builtin_amdgcn_readlane((int)wk, 63);
    int owner = (int)((~wlo) & 63u);
    lx = __int_as_float(__builtin_amdgcn_readlane(__float_as_int(bx), owner));
    ly = __int_as_float(__builtin_amdgcn_readlane(__float_as_int(by), owner));
    lz = __int_as_float(__builtin_amdgcn_readlane(__float_as_int(bz), owner));
    if (t == 0) {
      size_t o = ((size_t)b * M + r) * 3;
      newp[o] = lx; newp[o + 1] = ly; newp[o + 2] = lz;
    }
  }
}

// ---------------- KNN: one wave per query, top-16 smallest distances ----------------
__global__ void __launch_bounds__(256) knn_kernel(const float* __restrict__ p,
                                                  const float* __restrict__ newp,
                                                  int N, int M, int BM,
                                                  int* __restrict__ nidx) {
  int gwid = (blockIdx.x * 256 + threadIdx.x) >> 6;
  int lane = threadIdx.x & 63;
  if (gwid >= BM) return;
  int b = gwid / M;
  const float* pb = p + (size_t)b * N * 3;
  float qx = newp[(size_t)gwid * 3], qy = newp[(size_t)gwid * 3 + 1], qz = newp[(size_t)gwid * 3 + 2];
  float bd[16];
  int bi[16];
#pragma unroll
  for (int s = 0; s < 16; s++) { bd[s] = INFINITY; bi[s] = 0x7FFFFFFF; }
  for (int c = lane; c < N; c += 64) {
    float d = sqdist_exact(pb[3 * c] - qx, pb[3 * c + 1] - qy, pb[3 * c + 2] - qz);
    if (d < bd[15]) {
      bd[15] = d; bi[15] = c;
#pragma unroll
      for (int s = 15; s >= 1; --s) {
        bool sw = bd[s] < bd[s - 1];
        if (sw) {
          float tf = bd[s]; bd[s] = bd[s - 1]; bd[s - 1] = tf;
          int ti = bi[s]; bi[s] = bi[s - 1]; bi[s - 1] = ti;
        }
      }
    }
  }
  int out = 0;
  for (int r = 0; r < 16; r++) {
    float v = bd[0]; int ii = bi[0];
    float mv = v; int mi = ii;
#pragma unroll
    for (int m = 1; m < 64; m <<= 1) {
      float v2 = __shfl_xor(mv, m);
      int i2 = __shfl_xor(mi, m);
      if (v2 < mv || (v2 == mv && i2 < mi)) { mv = v2; mi = i2; }
    }
    if (mi == ii) {
#pragma unroll
      for (int s = 0; s < 15; s++) { bd[s] = bd[s + 1]; bi[s] = bi[s + 1]; }
      bd[15] = INFINITY; bi[15] = 0x7FFFFFFF;
    }
    if (lane == r) out = mi;
  }
  if (lane < 16) nidx[(size_t)gwid * 16 + lane] = out;
}

// ---------------- gather + GEMM + stats + max/min pool over k=16 ----------------
__global__ void __launch_bounds__(256) gemm_kernel(
    const float* __restrict__ p, const float* __restrict__ h, const float* __restrict__ newp,
    const int* __restrict__ nidx, const float* __restrict__ W,
    float* __restrict__ ymax, float* __restrict__ ymin, float* __restrict__ partial,
    int N, int M, int BM, int Ch, int Cpad, int D, int Gseq) {
  extern __shared__ float sm[];
  int Ctot = Ch + 3;
  int TD = D < 256 ? D : 256;
  int Gpar = 256 / TD;
  float* sfeat = sm;                      // Gpar*16*Cpad
  float* sstat = sm + Gpar * 16 * Cpad;   // 2*D
  int t = threadIdx.x;
  for (int i = t; i < 2 * D; i += 256) sstat[i] = 0.f;
  int mloc = t / TD;
  int dbase = t % TD;
  int DV = D / TD;  // 1 or 2
  __syncthreads();
  for (int s = 0; s < Gseq; s++) {
    int grp0 = (blockIdx.x * Gseq + s) * Gpar;
    if (grp0 >= BM) break;
    int nf = Gpar * 16 * Cpad;
    for (int i = t; i < nf; i += 256) {
      int c = i % Cpad;
      int rk = i / Cpad;
      int k = rk & 15;
      int g = rk >> 4;
      int grp = grp0 + g;
      float val = 0.f;
      if (grp < BM && c < Ctot) {
        int b = grp / M;
        int nb = nidx[(size_t)grp * 16 + k];
        if (c < 3)
          val = p[((size_t)b * N + nb) * 3 + c] - newp[(size_t)grp * 3 + c];
        else
          val = h[((size_t)b * N + nb) * Ch + (c - 3)];
      }
      sfeat[i] = val;
    }
    __syncthreads();
    int grp = grp0 + mloc;
    bool act = grp < BM;
    const float* fr = sfeat + mloc * 16 * Cpad;
    for (int dv = 0; dv < DV; ++dv) {
      int d = dbase + (dv << 8);
      float acc[16];
#pragma unroll
      for (int k = 0; k < 16; k++) acc[k] = 0.f;
      for (int c = 0; c < Cpad; c += 4) {
        float w0 = (c < Ctot) ? W[(size_t)c * D + d] : 0.f;
        float w1 = (c + 1 < Ctot) ? W[(size_t)(c + 1) * D + d] : 0.f;
        float w2 = (c + 2 < Ctot) ? W[(size_t)(c + 2) * D + d] : 0.f;
        float w3 = (c + 3 < Ctot) ? W[(size_t)(c + 3) * D + d] : 0.f;
#pragma unroll
        for (int k = 0; k < 16; k++) {
          const float4 f = *reinterpret_cast<const float4*>(fr + k * Cpad + c);
          acc[k] += f.x * w0 + f.y * w1 + f.z * w2 + f.w * w3;
        }
      }
      if (act) {
        float ssum = 0.f, ssq = 0.f, amax = -INFINITY, amin = INFINITY;
#pragma unroll
        for (int k = 0; k < 16; k++) {
          float a = acc[k];
          ssum += a; ssq += a * a;
          amax = fmaxf(amax, a); amin = fminf(amin, a);
        }
        ymax[(size_t)grp * D + d] = amax;
        ymin[(size_t)grp * D + d] = amin;
        atomicAdd(&sstat[d], ssum);
        atomicAdd(&sstat[D + d], ssq);
      }
    }
    __syncthreads();
  }
  for (int i = t; i < 2 * D; i += 256)
    atomicAdd(&partial[(blockIdx.x & 63) * 2 * D + i], sstat[i]);
}

// ---------------- classifier head: mean-pool + 3 layers, single block ----------------
__global__ void __launch_bounds__(512) classifier_kernel(
    const float* __restrict__ h4,
    const float* __restrict__ Wc1, const float* __restrict__ bc1,
    const float* __restrict__ gc1, const float* __restrict__ hc1,
    const float* __restrict__ Wc2, const float* __restrict__ bc2,
    const float* __restrict__ gc2, const float* __restrict__ hc2,
    const float* __restrict__ Wc3, const float* __restrict__ bc3,
    float* __restrict__ out) {
  __shared__ float z[16 * 512];
  __shared__ float z1[16 * 256];
  __shared__ float z2[16 * 128];
  __shared__ float sc[256], sh[256];
  int t = threadIdx.x;
  for (int i = t; i < 16 * 512; i += 512) {
    int b = i >> 9, c = i & 511;
    float s = 0.f;
    for (int k = 0; k < 16; k++) s += h4[((size_t)b * 16 + k) * 512 + c];
    z[i] = s * (1.f / 16.f);
  }
  __syncthreads();
  for (int i = t; i < 16 * 256; i += 512) {
    int b = i >> 8, d = i & 255;
    float a = bc1[d];
    for (int c = 0; c < 512; c++) a += z[(b << 9) + c] * Wc1[c * 256 + d];
    z1[i] = a;
  }
  __syncthreads();
  if (t < 256) {
    float s = 0.f, q = 0.f;
    for (int b = 0; b < 16; b++) { float a = z1[(b << 8) + t]; s += a; q += a * a; }
    float mean = s * (1.f / 16.f);
    float var = fmaxf(q * (1.f / 16.f) - mean * mean, 0.f);
    float scl = gc1[t] * rsqrtf(var + BN_EPS);
    sc[t] = scl; sh[t] = hc1[t] - mean * scl;
  }
  __syncthreads();
  for (int i = t; i < 16 * 256; i += 512) {
    int d = i & 255;
    z1[i] = fmaxf(z1[i] * sc[d] + sh[d], 0.f);
  }
  __syncthreads();
  for (int i = t; i < 16 * 128; i += 512) {
    int b = i >> 7, d = i & 127;
    float a = bc2[d];
    for (int c = 0; c < 256; c++) a += z1[(b << 8) + c] * Wc2[c * 128 + d];
    z2[i] = a;
  }
  __syncthreads();
  if (t < 128) {
    float s = 0.f, q = 0.f;
    for (int b = 0; b < 16; b++) { float a = z2[(b << 7) + t]; s += a; q += a * a; }
    float mean = s * (1.f / 16.f);
    float var = fmaxf(q * (1.f / 16.f) - mean * mean, 0.f);
    float scl = gc2[t] * rsqrtf(var + BN_EPS);
    sc[t] = scl; sh[t] = hc2[t] - mean * scl;
  }
  __syncthreads();
  for (int i = t; i < 16 * 128; i += 512) {
    int d = i & 127;
    z2[i] = fmaxf(z2[i] * sc[d] + sh[d], 0.f);
  }
  __syncthreads();
  for (int i = t; i < 640; i += 512) {
    int b = i / 40, d = i % 40;
    float a = bc3[d];
    for (int c = 0; c < 128; c++) a += z2[(b << 7) + c] * Wc3[c * 40 + d];
    out[i] = a;
  }
}

extern "C" void kernel_launch(void* const* d_in, const int* in_sizes, int n_in,
                              void* d_out, int out_size, void* d_ws, size_t ws_size,
                              hipStream_t stream) {
  (void)in_sizes; (void)n_in; (void)out_size; (void)ws_size;
  const float* x   = (const float*)d_in[0];
  const float* W1  = (const float*)d_in[1];
  const float* g1  = (const float*)d_in[2];
  const float* b1  = (const float*)d_in[3];
  const float* W2  = (const float*)d_in[4];
  const float* g2  = (const float*)d_in[5];
  const float* b2  = (const float*)d_in[6];
  const float* W3  = (const float*)d_in[7];
  const float* g3  = (const float*)d_in[8];
  const float* b3  = (const float*)d_in[9];
  const float* W4  = (const float*)d_in[10];
  const float* g4  = (const float*)d_in[11];
  const float* b4  = (const float*)d_in[12];
  const float* W5  = (const float*)d_in[13];
  const float* g5  = (const float*)d_in[14];
  const float* b5  = (const float*)d_in[15];
  const float* Wc1 = (const float*)d_in[16];
  const float* bc1 = (const float*)d_in[17];
  const float* gc1 = (const float*)d_in[18];
  const float* hc1 = (const float*)d_in[19];
  const float* Wc2 = (const float*)d_in[20];
  const float* bc2 = (const float*)d_in[21];
  const float* gc2 = (const float*)d_in[22];
  const float* hc2 = (const float*)d_in[23];
  const float* Wc3 = (const float*)d_in[24];
  const float* bc3 = (const float*)d_in[25];
  float* out = (float*)d_out;

  float* ws = (float*)d_ws;
  float* HA   = ws;                  // 2,097,152 (h1; stage2 out; stage4 out)
  float* HB   = HA + 2097152;        // 1,048,576 (stage1 out; stage3 out)
  float* YMIN = HB + 1048576;        // 1,048,576
  float* NP1  = YMIN + 1048576;      // 49,152
  float* NP2  = NP1 + 49152;         // 12,288
  float* NP3  = NP2 + 12288;         // 3,072
  float* NP4  = NP3 + 3072;          // 768
  int*   NIDX = (int*)(NP4 + 768);   // 262,144 ints
  float* PART = (float*)(NIDX + 262144);  // 5 * 65,536
  float* SS   = PART + 5 * 65536;         // 5 * 1,024

  hipMemsetAsync(PART, 0, 5 * 65536 * sizeof(float), stream);

  // --- MLP1 + BN(axes 0,1) + ReLU ---
  mlp1_kernel<<<(65536 * 32) / 256, 256, 0, stream>>>(x, W1, HA, 65536);
  stats_kernel<<<256, 256, 2 * 32 * sizeof(float), stream>>>(HA, 65536 * 32, 32, PART);
  finalize_kernel<<<1, 32, 0, stream>>>(PART, g1, b1, 65536.f, 32, SS);
  bn_apply_kernel<<<512, 256, 0, stream>>>(HA, HA, SS, 32, 65536 * 32);

  // --- stage 1: N=4096 -> M=1024, Ch=32 -> D=64 ---
  fps6_kernel<<<16, 512, 0, stream>>>(x, NP1);
  knn_kernel<<<(16384 + 3) / 4, 256, 0, stream>>>(x, NP1, 4096, 1024, 16384, NIDX);
  gemm_kernel<<<512, 256, (4 * 16 * 36 + 2 * 64) * sizeof(float), stream>>>(
      x, HA, NP1, NIDX, W2, HB, YMIN, PART + 65536, 4096, 1024, 16384, 32, 36, 64, 8);
  finalize_kernel<<<1, 64, 0, stream>>>(PART + 65536, g2, b2, (float)(16384 * 16), 64, SS + 1024);
  bn_apply_kernel<<<512, 256, 0, stream>>>(HB, YMIN, SS + 1024, 64, 16384 * 64);

  // --- stage 2: N=1024 -> M=256, Ch=64 -> D=128 ---
  fps5_kernel<16><<<16, 64, 0, stream>>>(NP1, NP2);
  knn_kernel<<<(4096 + 3) / 4, 256, 0, stream>>>(NP1, NP2, 1024, 256, 4096, NIDX);
  gemm_kernel<<<512, 256, (2 * 16 * 68 + 2 * 128) * sizeof(float), stream>>>(
      NP1, HB, NP2, NIDX, W3, HA, YMIN, PART + 2 * 65536, 1024, 256, 4096, 64, 68, 128, 4);
  finalize_kernel<<<1, 128, 0, stream>>>(PART + 2 * 65536, g3, b3, (float)(4096 * 16), 128, SS + 2048);
  bn_apply_kernel<<<512, 256, 0, stream>>>(HA, YMIN, SS + 2048, 128, 4096 * 128);

  // --- stage 3: N=256 -> M=64, Ch=128 -> D=256 ---
  fps5_kernel<4><<<16, 64, 0, stream>>>(NP2, NP3);
  knn_kernel<<<(1024 + 3) / 4, 256, 0, stream>>>(NP2, NP3, 256, 64, 1024, NIDX);
  gemm_kernel<<<512, 256, (16 * 132 + 2 * 256) * sizeof(float), stream>>>(
      NP2, HA, NP3, NIDX, W4, HB, YMIN, PART + 3 * 65536, 256, 64, 1024, 128, 132, 256, 2);
  finalize_kernel<<<1, 256, 0, stream>>>(PART + 3 * 65536, g4, b4, (float)(1024 * 16), 256, SS + 3072);
  bn_apply_kernel<<<512, 256, 0, stream>>>(HB, YMIN, SS + 3072, 256, 1024 * 256);

  // --- stage 4: N=64 -> M=16, Ch=256 -> D=512 ---
  fps5_kernel<1><<<16, 64, 0, stream>>>(NP3, NP4);
  knn_kernel<<<(256 + 3) / 4, 256, 0, stream>>>(NP3, NP4, 64, 16, 256, NIDX);
  gemm_kernel<<<256, 256, (16 * 260 + 2 * 512) * sizeof(float), stream>>>(
      NP3, HB, NP4, NIDX, W5, HA, YMIN, PART + 4 * 65536, 64, 16, 256, 256, 260, 512, 1);
  finalize_kernel<<<1, 512, 0, stream>>>(PART + 4 * 65536, g5, b5, (float)(256 * 16), 512, SS + 4096);
  bn_apply_kernel<<<512, 256, 0, stream>>>(HA, YMIN, SS + 4096, 512, 256 * 512);

  // --- classifier head ---
  classifier_kernel<<<1, 512, 0, stream>>>(HA, Wc1, bc1, gc1, hc1, Wc2, bc2, gc2, hc2, Wc3, bc3, out);
}